// Round 1
// baseline (62.185 us; speedup 1.0000x reference)
//
#include <hip/hip_runtime.h>
#include <hip/hip_bf16.h>

// out[i][j][o] = sum_h X[i+1][h] * X[j+1][h] * W[o][h] + b[o]
// (diff/W2 term cancels under symmetrization; only W[:, :768] is live)
//
// Single-shot design: entire K=768 of all three operand tiles staged to LDS
// once (145.5 KB), 512 threads = 8 waves = 2 waves/SIMD (vs 1 before),
// 4 output quadrants x 2-way K-split, 3 barriers total (vs 6).
// X: (512, 768) fp32, W: (2, 1536) fp32, b: (2,) fp32, out: (510, 510, 2) fp32

constexpr int H   = 768;
constexpr int M   = 510;
constexpr int LDP = H + 8;   // 776 elems = 1552 B row stride: 4-bank rotation,
                             // 16B-aligned rows (1552 = 16*97)

typedef __attribute__((ext_vector_type(8))) short short8;   // 8 bf16 = 4 VGPRs
typedef __attribute__((ext_vector_type(4))) float f32x4;

__device__ inline void cvt_store4(unsigned short* p, float4 v) {
  __hip_bfloat162 lo = __float22bfloat162_rn(make_float2(v.x, v.y));  // packed RNE
  __hip_bfloat162 hi = __float22bfloat162_rn(make_float2(v.z, v.w));
  uint2 u;
  u.x = *(unsigned int*)&lo;
  u.y = *(unsigned int*)&hi;
  *(uint2*)p = u;   // ds_write_b64
}

__device__ inline float4 mul4(float4 a, float4 b) {
  return make_float4(a.x * b.x, a.y * b.y, a.z * b.z, a.w * b.w);
}

__global__ __launch_bounds__(512, 1) void pairwise_head_mfma(
    const float* __restrict__ X, const float* __restrict__ W,
    const float* __restrict__ bias, float* __restrict__ out) {
  __shared__ __align__(16) unsigned short sm[3 * 32 * LDP];  // 148,992 B
  unsigned short* sA0 = sm;                 // rows-i, * w0
  unsigned short* sA1 = sm + 32 * LDP;      // rows-i, * w1
  unsigned short* sB  = sm + 2 * 32 * LDP;  // rows-j, raw

  const int tid = threadIdx.x;
  const int gi0 = blockIdx.y * 32;
  const int gj0 = blockIdx.x * 32;

  // ---- single-shot staging: 16 threads/row, full K=768 at once ----
  // thread covers elems [u*128 + sc*4, +4) and [u*128 + 64 + sc*4, +4), u=0..5
  const int srow = tid >> 4;    // 0..31
  const int sc   = tid & 15;    // 0..15
  int arow = gi0 + 1 + srow; if (arow > 511) arow = 511;  // clamp; output masked
  int brow = gj0 + 1 + srow; if (brow > 511) brow = 511;
  const float4* Xa = (const float4*)(X + (size_t)arow * H);
  const float4* Xb = (const float4*)(X + (size_t)brow * H);
  const float4* W0 = (const float4*)(W);
  const float4* W1 = (const float4*)(W + 1536);
  unsigned short* a0p = sA0 + srow * LDP + sc * 4;
  unsigned short* a1p = sA1 + srow * LDP + sc * 4;
  unsigned short* bp  = sB  + srow * LDP + sc * 4;

#pragma unroll
  for (int u = 0; u < 6; ++u) {
    const int cl = u * 32 + sc;                    // dense: 16 lanes = 256 B
    float4 xa0 = Xa[cl], xa1 = Xa[cl + 16];
    float4 xb0 = Xb[cl], xb1 = Xb[cl + 16];
    float4 w00 = W0[cl], w01 = W0[cl + 16];
    float4 w10 = W1[cl], w11 = W1[cl + 16];
    cvt_store4(a0p + u * 128,      mul4(xa0, w00));
    cvt_store4(a0p + u * 128 + 64, mul4(xa1, w01));
    cvt_store4(a1p + u * 128,      mul4(xa0, w10));
    cvt_store4(a1p + u * 128 + 64, mul4(xa1, w11));
    cvt_store4(bp  + u * 128,      xb0);
    cvt_store4(bp  + u * 128 + 64, xb1);
  }
  __syncthreads();

  // ---- compute: 8 waves = 4 quadrants (mi,nj) x 2 K-halves (kh) ----
  const int wave = tid >> 6;
  const int lane = tid & 63;
  const int lo = lane & 15;     // frag row (A) / col (B)
  const int q  = lane >> 4;     // quad -> k-subgroup
  const int quad = wave & 3;
  const int kh   = wave >> 2;   // K-half: [kh*384, kh*384+384)
  const int mi = quad >> 1;
  const int nj = quad & 1;
  const unsigned short* pa0 = sA0 + (mi * 16 + lo) * LDP + kh * 384 + q * 8;
  const unsigned short* pa1 = sA1 + (mi * 16 + lo) * LDP + kh * 384 + q * 8;
  const unsigned short* pb  = sB  + (nj * 16 + lo) * LDP + kh * 384 + q * 8;

  f32x4 acc0 = {0.f, 0.f, 0.f, 0.f};
  f32x4 acc1 = {0.f, 0.f, 0.f, 0.f};
#pragma unroll
  for (int c = 0; c < 12; ++c) {        // 12 chunks of K=32 per K-half
    const short8 a0 = *(const short8*)(pa0 + c * 32);
    const short8 a1 = *(const short8*)(pa1 + c * 32);
    const short8 b  = *(const short8*)(pb  + c * 32);
    acc0 = __builtin_amdgcn_mfma_f32_16x16x32_bf16(a0, b, acc0, 0, 0, 0);
    acc1 = __builtin_amdgcn_mfma_f32_16x16x32_bf16(a1, b, acc1, 0, 0, 0);
  }

  __syncthreads();   // all LDS reads done; sm reusable as reduce buffer

  // ---- 2-way K reduction through LDS (8,704 B, aliases sm) ----
  // layout: [quad][16 rows][17 float2-slots] (pad 17 breaks bank alias)
  float* red = (float*)sm;
  if (kh == 1) {
#pragma unroll
    for (int r = 0; r < 4; ++r) {
      const int rl = q * 4 + r;
      float2 v = make_float2(acc0[r], acc1[r]);
      *(float2*)(red + ((quad * 16 + rl) * 17 + lo) * 2) = v;
    }
  }
  __syncthreads();

  // ---- epilogue (kh=0 waves): add partner partial + bias, store ----
  // D layout col=lane&15, row=quad4*4+reg (proven)
  if (kh == 0) {
    const float b0 = bias[0];
    const float b1 = bias[1];
    const int j  = gj0 + nj * 16 + lo;
    const int i0 = gi0 + mi * 16 + q * 4;
    if (j < M) {
#pragma unroll
      for (int r = 0; r < 4; ++r) {
        const int i = i0 + r;
        if (i < M) {
          const float2 p =
              *(const float2*)(red + ((quad * 16 + (q * 4 + r)) * 17 + lo) * 2);
          float2 v = make_float2(acc0[r] + p.x + b0, acc1[r] + p.y + b1);
          *(float2*)(out + ((size_t)i * M + j) * 2) = v;  // coalesced 128B/quad
        }
      }
    }
  }
}

extern "C" void kernel_launch(void* const* d_in, const int* in_sizes, int n_in,
                              void* d_out, int out_size, void* d_ws, size_t ws_size,
                              hipStream_t stream) {
  const float* X    = (const float*)d_in[0];  // (1, 512, 768)
  const float* W    = (const float*)d_in[1];  // (2, 1536)
  const float* bias = (const float*)d_in[2];  // (2,)
  float* out = (float*)d_out;                 // (510, 510, 2)

  dim3 grid(16, 16);
  dim3 block(512);
  hipLaunchKernelGGL(pairwise_head_mfma, grid, block, 0, stream,
                     X, W, bias, out);
}